// Round 2
// baseline (589.980 us; speedup 1.0000x reference)
//
#include <hip/hip_runtime.h>
#include <math.h>

#define NN 50000
#define EE 800000
#define FIN 96
#define FHID 384
#define FOUT 192
#define BN_EPS 1e-5f

// ---------------- SpMM: agg[row[e]] += val[e] * x[col[e]] ----------------
// 32 lanes per edge, 3 floats per lane (96 = 32*3). 76.8M fp32 atomics.
__global__ __launch_bounds__(256) void spmm_kernel(
    const float* __restrict__ x, const float* __restrict__ val,
    const int* __restrict__ row, const int* __restrict__ col,
    float* __restrict__ agg)
{
    int gid = blockIdx.x * 256 + threadIdx.x;
    int e = gid >> 5;
    if (e >= EE) return;
    int lane = gid & 31;
    int r = row[e], c = col[e];
    float v = val[e];
    const float* xr = x + (size_t)c * FIN;
    float* ar = agg + (size_t)r * FIN;
    atomicAdd(ar + lane,      v * xr[lane]);
    atomicAdd(ar + lane + 32, v * xr[lane + 32]);
    atomicAdd(ar + lane + 64, v * xr[lane + 64]);
}

// ---------------- GEMM1: h1 = (agg + eps*x) @ W1 + b1, + column stats ----
// tile 64x128, K=96 whole. 256 thr, each 4x8.
__global__ __launch_bounds__(256) void gemm1_kernel(
    const float* __restrict__ agg, const float* __restrict__ x,
    const float* __restrict__ W1, const float* __restrict__ b1,
    const float* __restrict__ epsp,
    float* __restrict__ h1, float* __restrict__ sum1, float* __restrict__ sq1)
{
    __shared__ float As[64 * 97];   // [m][k], stride 97; reused for stats
    __shared__ float Bs[96 * 128];  // [k][n]
    int tid = threadIdx.x;
    int tx = tid & 15, ty = tid >> 4;
    int row0 = blockIdx.x * 64;
    int n0 = blockIdx.y * 128;
    float eps = epsp[0];

    // Load A tile (v = agg + eps*x), float4 global loads, zero-pad OOB rows
    for (int i4 = tid; i4 < 64 * 24; i4 += 256) {
        int m = i4 / 24;
        int k4 = (i4 - m * 24) * 4;
        int gm = row0 + m;
        float a0 = 0.f, a1 = 0.f, a2 = 0.f, a3 = 0.f;
        if (gm < NN) {
            size_t off = (size_t)gm * FIN + k4;
            float4 ag = *(const float4*)(agg + off);
            float4 xx = *(const float4*)(x + off);
            a0 = ag.x + eps * xx.x; a1 = ag.y + eps * xx.y;
            a2 = ag.z + eps * xx.z; a3 = ag.w + eps * xx.w;
        }
        float* dst = As + m * 97 + k4;
        dst[0] = a0; dst[1] = a1; dst[2] = a2; dst[3] = a3;
    }
    // Load B tile (96 x 128)
    for (int i4 = tid; i4 < 96 * 32; i4 += 256) {
        int kb = i4 >> 5;
        int nb4 = (i4 & 31) * 4;
        *(float4*)(Bs + kb * 128 + nb4) =
            *(const float4*)(W1 + (size_t)kb * FHID + n0 + nb4);
    }
    __syncthreads();

    float acc[4][8];
    #pragma unroll
    for (int r = 0; r < 4; ++r)
        #pragma unroll
        for (int c = 0; c < 8; ++c) acc[r][c] = 0.f;

    #pragma unroll 4
    for (int k = 0; k < 96; ++k) {
        float a[4];
        a[0] = As[(ty*4+0)*97 + k];
        a[1] = As[(ty*4+1)*97 + k];
        a[2] = As[(ty*4+2)*97 + k];
        a[3] = As[(ty*4+3)*97 + k];
        float4 bA = *(const float4*)(Bs + k*128 + tx*4);
        float4 bB = *(const float4*)(Bs + k*128 + 64 + tx*4);
        float b[8] = {bA.x,bA.y,bA.z,bA.w,bB.x,bB.y,bB.z,bB.w};
        #pragma unroll
        for (int r = 0; r < 4; ++r)
            #pragma unroll
            for (int c = 0; c < 8; ++c)
                acc[r][c] = fmaf(a[r], b[c], acc[r][c]);
    }

    // epilogue: bias, store h1, column stats (sum, sumsq) over valid rows
    float4 bb0 = *(const float4*)(b1 + n0 + tx*4);
    float4 bb1 = *(const float4*)(b1 + n0 + 64 + tx*4);
    float bv[8] = {bb0.x,bb0.y,bb0.z,bb0.w,bb1.x,bb1.y,bb1.z,bb1.w};
    float cs[8], cq[8];
    #pragma unroll
    for (int c = 0; c < 8; ++c) { cs[c] = 0.f; cq[c] = 0.f; }
    #pragma unroll
    for (int r = 0; r < 4; ++r) {
        int gm = row0 + ty*4 + r;
        if (gm < NN) {
            float v[8];
            #pragma unroll
            for (int c = 0; c < 8; ++c) {
                v[c] = acc[r][c] + bv[c];
                cs[c] += v[c];
                cq[c] += v[c]*v[c];
            }
            float* o = h1 + (size_t)gm * FHID + n0;
            *(float4*)(o + tx*4)      = make_float4(v[0],v[1],v[2],v[3]);
            *(float4*)(o + 64 + tx*4) = make_float4(v[4],v[5],v[6],v[7]);
        }
    }
    __syncthreads();   // all As reads done; reuse for stats
    #pragma unroll
    for (int j = 0; j < 4; ++j) {
        As[ty*128 + tx*4 + j]        = cs[j];
        As[ty*128 + 64 + tx*4 + j]   = cs[4+j];
        As[2048 + ty*128 + tx*4 + j]      = cq[j];
        As[2048 + ty*128 + 64 + tx*4 + j] = cq[4+j];
    }
    __syncthreads();
    if (tid < 128) {
        float s = 0.f;
        #pragma unroll
        for (int t = 0; t < 16; ++t) s += As[t*128 + tid];
        atomicAdd(sum1 + n0 + tid, s);
    } else {
        int c = tid - 128;
        float q = 0.f;
        #pragma unroll
        for (int t = 0; t < 16; ++t) q += As[2048 + t*128 + c];
        atomicAdd(sq1 + n0 + c, q);
    }
}

// ---------------- GEMM2: out_pre = elu(bn1(h1)) @ W2 + b2, + stats2 ------
__global__ __launch_bounds__(256) void gemm2_kernel(
    const float* __restrict__ h1, const float* __restrict__ W2,
    const float* __restrict__ b2,
    const float* __restrict__ g1, const float* __restrict__ be1,
    const float* __restrict__ sum1, const float* __restrict__ sq1,
    float* __restrict__ out, float* __restrict__ sum2, float* __restrict__ sq2)
{
    __shared__ float As[64 * 33];  // [m][kk], stride 33; reused for stats
    __shared__ float Bs[32 * 64];  // [kk][n]
    int tid = threadIdx.x;
    int tx = tid & 15, ty = tid >> 4;
    int row0 = blockIdx.x * 64;
    int n0 = blockIdx.y * 64;
    const float invN = 1.f / NN;

    float acc[4][4];
    #pragma unroll
    for (int r = 0; r < 4; ++r)
        #pragma unroll
        for (int c = 0; c < 4; ++c) acc[r][c] = 0.f;

    for (int k0 = 0; k0 < FHID; k0 += 32) {
        // A tile with BN1 + ELU
        for (int i4 = tid; i4 < 64 * 8; i4 += 256) {
            int m = i4 >> 3;
            int kk4 = (i4 & 7) * 4;
            int gm = row0 + m;
            float av[4] = {0.f, 0.f, 0.f, 0.f};
            if (gm < NN) {
                float4 h = *(const float4*)(h1 + (size_t)gm * FHID + k0 + kk4);
                float hv[4] = {h.x, h.y, h.z, h.w};
                #pragma unroll
                for (int j = 0; j < 4; ++j) {
                    int k = k0 + kk4 + j;
                    float mean = sum1[k] * invN;
                    float var  = sq1[k] * invN - mean*mean;
                    float inv  = rsqrtf(var + BN_EPS);
                    float t = g1[k] * (hv[j] - mean) * inv + be1[k];
                    av[j] = t > 0.f ? t : expf(t) - 1.f;
                }
            }
            float* dst = As + m*33 + kk4;
            dst[0]=av[0]; dst[1]=av[1]; dst[2]=av[2]; dst[3]=av[3];
        }
        // B tile
        for (int i4 = tid; i4 < 32 * 16; i4 += 256) {
            int kb = i4 >> 4;
            int nb4 = (i4 & 15) * 4;
            *(float4*)(Bs + kb*64 + nb4) =
                *(const float4*)(W2 + (size_t)(k0+kb) * FOUT + n0 + nb4);
        }
        __syncthreads();
        #pragma unroll 8
        for (int kk = 0; kk < 32; ++kk) {
            float a[4];
            a[0] = As[(ty*4+0)*33 + kk];
            a[1] = As[(ty*4+1)*33 + kk];
            a[2] = As[(ty*4+2)*33 + kk];
            a[3] = As[(ty*4+3)*33 + kk];
            float4 b = *(const float4*)(Bs + kk*64 + tx*4);
            float bvv[4] = {b.x,b.y,b.z,b.w};
            #pragma unroll
            for (int r = 0; r < 4; ++r)
                #pragma unroll
                for (int c = 0; c < 4; ++c)
                    acc[r][c] = fmaf(a[r], bvv[c], acc[r][c]);
        }
        __syncthreads();
    }

    // epilogue: bias, store pre-activation to out, stats2
    float4 bb = *(const float4*)(b2 + n0 + tx*4);
    float bv[4] = {bb.x, bb.y, bb.z, bb.w};
    float cs[4] = {0,0,0,0}, cq[4] = {0,0,0,0};
    #pragma unroll
    for (int r = 0; r < 4; ++r) {
        int gm = row0 + ty*4 + r;
        if (gm < NN) {
            float v[4];
            #pragma unroll
            for (int c = 0; c < 4; ++c) {
                v[c] = acc[r][c] + bv[c];
                cs[c] += v[c];
                cq[c] += v[c]*v[c];
            }
            *(float4*)(out + (size_t)gm * FOUT + n0 + tx*4) =
                make_float4(v[0], v[1], v[2], v[3]);
        }
    }
    #pragma unroll
    for (int j = 0; j < 4; ++j) {
        As[ty*64 + tx*4 + j]        = cs[j];
        As[1024 + ty*64 + tx*4 + j] = cq[j];
    }
    __syncthreads();
    if (tid < 64) {
        float s = 0.f;
        #pragma unroll
        for (int t = 0; t < 16; ++t) s += As[t*64 + tid];
        atomicAdd(sum2 + n0 + tid, s);
    } else if (tid < 128) {
        int c = tid - 64;
        float q = 0.f;
        #pragma unroll
        for (int t = 0; t < 16; ++t) q += As[1024 + t*64 + c];
        atomicAdd(sq2 + n0 + c, q);
    }
}

// ---------------- BN2 + ELU, in-place on d_out ---------------------------
__global__ __launch_bounds__(256) void bn2_elu_kernel(
    float* __restrict__ out, const float* __restrict__ g2,
    const float* __restrict__ be2,
    const float* __restrict__ sum2, const float* __restrict__ sq2)
{
    int gid = blockIdx.x * 256 + threadIdx.x;
    if (gid >= NN * FOUT / 4) return;
    size_t base = (size_t)gid * 4;
    int c0 = (int)(base % FOUT);
    float4 h = *(float4*)(out + base);
    float hv[4] = {h.x, h.y, h.z, h.w};
    float rv[4];
    #pragma unroll
    for (int j = 0; j < 4; ++j) {
        int c = c0 + j;
        float mean = sum2[c] * (1.f / NN);
        float var  = sq2[c] * (1.f / NN) - mean*mean;
        float inv  = rsqrtf(var + BN_EPS);
        float t = g2[c] * (hv[j] - mean) * inv + be2[c];
        rv[j] = t > 0.f ? t : expf(t) - 1.f;
    }
    *(float4*)(out + base) = make_float4(rv[0], rv[1], rv[2], rv[3]);
}

// zero-fill fallback so an undersized workspace fails validation loudly
// instead of writing OOB and killing the container
__global__ __launch_bounds__(256) void zero_out_kernel(float* out, int n) {
    int gid = blockIdx.x * 256 + threadIdx.x;
    if (gid < n) out[gid] = 0.f;
}

extern "C" void kernel_launch(void* const* d_in, const int* in_sizes, int n_in,
                              void* d_out, int out_size, void* d_ws, size_t ws_size,
                              hipStream_t stream) {
    const float* x    = (const float*)d_in[0];
    const float* val  = (const float*)d_in[1];
    const float* W1   = (const float*)d_in[2];
    const float* b1   = (const float*)d_in[3];
    const float* g1   = (const float*)d_in[4];
    const float* be1  = (const float*)d_in[5];
    const float* W2   = (const float*)d_in[6];
    const float* b2   = (const float*)d_in[7];
    const float* g2   = (const float*)d_in[8];
    const float* be2  = (const float*)d_in[9];
    const float* epsp = (const float*)d_in[10];
    const int* row    = (const int*)d_in[11];
    const int* col    = (const int*)d_in[12];
    float* out = (float*)d_out;

    // ws layout (floats): [0:384) sum1 | [384:768) sq1 | [768:960) sum2 |
    // [960:1152) sq2 | pad | [2048 : +4.8M) agg | h1 19.2M  => ~96.2 MB
    const size_t need = (2048 + (size_t)NN * FIN + (size_t)NN * FHID) * sizeof(float);
    if (ws_size < need) {
        zero_out_kernel<<<(out_size + 255) / 256, 256, 0, stream>>>(out, out_size);
        return;
    }

    float* ws   = (float*)d_ws;
    float* sum1 = ws;
    float* sq1  = ws + 384;
    float* sum2 = ws + 768;
    float* sq2  = ws + 960;
    float* agg  = ws + 2048;
    float* h1   = agg + (size_t)NN * FIN;

    // zero stats + agg (harness poisons ws with 0xAA before every launch)
    hipMemsetAsync(d_ws, 0, (2048 + (size_t)NN * FIN) * sizeof(float), stream);

    spmm_kernel<<<(EE * 32) / 256, 256, 0, stream>>>(x, val, row, col, agg);

    dim3 grid1((NN + 63) / 64, 3, 1);
    gemm1_kernel<<<grid1, 256, 0, stream>>>(agg, x, W1, b1, epsp, h1, sum1, sq1);

    dim3 grid2((NN + 63) / 64, 3, 1);
    gemm2_kernel<<<grid2, 256, 0, stream>>>(h1, W2, b2, g1, be1, sum1, sq1,
                                            out, sum2, sq2);

    bn2_elu_kernel<<<(NN * FOUT / 4 + 255) / 256, 256, 0, stream>>>(
        out, g2, be2, sum2, sq2);
}

// Round 3
// 465.253 us; speedup vs baseline: 1.2681x; 1.2681x over previous
//
#include <hip/hip_runtime.h>
#include <math.h>

#define NN 50000
#define EE 800000
#define FIN 96
#define FHID 384
#define FOUT 192
#define BN_EPS 1e-5f
#define NBLK_SCAN 196   // ceil(NN/256)

// ---------------- CSR build: histogram ----------------
__global__ __launch_bounds__(256) void hist_kernel(
    const int* __restrict__ row, int* __restrict__ deg)
{
    int i = blockIdx.x * 256 + threadIdx.x;
    if (i < EE) atomicAdd(&deg[row[i]], 1);
}

// per-block totals of deg
__global__ __launch_bounds__(256) void scan_partial_kernel(
    const int* __restrict__ deg, int* __restrict__ bsum)
{
    __shared__ int s[256];
    int t = threadIdx.x;
    int i = blockIdx.x * 256 + t;
    s[t] = (i < NN) ? deg[i] : 0;
    __syncthreads();
    #pragma unroll
    for (int o = 128; o > 0; o >>= 1) {
        if (t < o) s[t] += s[t + o];
        __syncthreads();
    }
    if (t == 0) bsum[blockIdx.x] = s[0];
}

// exclusive scan of the 196 block totals (single block)
__global__ __launch_bounds__(256) void scan_tot_kernel(
    int* __restrict__ bsum, int* __restrict__ offsets)
{
    __shared__ int s[256];
    int t = threadIdx.x;
    int v = (t < NBLK_SCAN) ? bsum[t] : 0;
    s[t] = v;
    __syncthreads();
    for (int o = 1; o < 256; o <<= 1) {
        int add = (t >= o) ? s[t - o] : 0;
        __syncthreads();
        s[t] += add;
        __syncthreads();
    }
    if (t < NBLK_SCAN) bsum[t] = s[t] - v;   // exclusive block offset
    if (t == 255) offsets[NN] = s[255];      // total == EE
}

// final: offsets[i] = exclusive scan; cursor[i] = same (cursor aliases deg)
__global__ __launch_bounds__(256) void scan_final_kernel(
    int* deg_and_cursor, const int* __restrict__ bsum, int* __restrict__ offsets)
{
    __shared__ int s[256];
    int t = threadIdx.x;
    int i = blockIdx.x * 256 + t;
    int v = (i < NN) ? deg_and_cursor[i] : 0;
    s[t] = v;
    __syncthreads();   // all reads of deg done before any write below
    for (int o = 1; o < 256; o <<= 1) {
        int add = (t >= o) ? s[t - o] : 0;
        __syncthreads();
        s[t] += add;
        __syncthreads();
    }
    int excl = s[t] - v + bsum[blockIdx.x];
    if (i < NN) {
        offsets[i] = excl;
        deg_and_cursor[i] = excl;   // becomes the scatter cursor
    }
}

// scatter edge payloads into CSR slots
__global__ __launch_bounds__(256) void scatter_kernel(
    const int* __restrict__ row, const int* __restrict__ col,
    const float* __restrict__ val, int* cursor,
    int* __restrict__ ecol, float* __restrict__ eval)
{
    int i = blockIdx.x * 256 + threadIdx.x;
    if (i >= EE) return;
    int r = row[i];
    int p = atomicAdd(&cursor[r], 1);
    ecol[p] = col[i];
    eval[p] = val[i];
}

// ---------------- gather-aggregate: agg[r] = sum val*x[col] + eps*x[r] ----
// 32 lanes per row, 3 floats per lane. No atomics.
__global__ __launch_bounds__(256) void gather_kernel(
    const float* __restrict__ x, const int* __restrict__ offsets,
    const int* __restrict__ ecol, const float* __restrict__ eval,
    const float* __restrict__ epsp, float* __restrict__ agg)
{
    int rid = blockIdx.x * 8 + (threadIdx.x >> 5);
    if (rid >= NN) return;
    int lane = threadIdx.x & 31;
    int beg = offsets[rid], end = offsets[rid + 1];
    float a0 = 0.f, a1 = 0.f, a2 = 0.f;
    for (int j = beg; j < end; ++j) {
        int c = ecol[j];
        float v = eval[j];
        const float* xr = x + (size_t)c * FIN;
        a0 += v * xr[lane];
        a1 += v * xr[lane + 32];
        a2 += v * xr[lane + 64];
    }
    float e = epsp[0];
    const float* xs = x + (size_t)rid * FIN;
    a0 += e * xs[lane];
    a1 += e * xs[lane + 32];
    a2 += e * xs[lane + 64];
    float* ar = agg + (size_t)rid * FIN;
    ar[lane] = a0; ar[lane + 32] = a1; ar[lane + 64] = a2;
}

// ---------------- GEMM1: h1 = agg @ W1 + b1, + column stats --------------
// tile 64x128, K=96 whole. agg already contains the eps self-loop.
__global__ __launch_bounds__(256) void gemm1_kernel(
    const float* __restrict__ agg,
    const float* __restrict__ W1, const float* __restrict__ b1,
    float* __restrict__ h1, float* __restrict__ sum1, float* __restrict__ sq1)
{
    __shared__ float As[64 * 97];   // [m][k]; reused for stats
    __shared__ float Bs[96 * 128];  // [k][n]
    int tid = threadIdx.x;
    int tx = tid & 15, ty = tid >> 4;
    int row0 = blockIdx.x * 64;
    int n0 = blockIdx.y * 128;

    for (int i4 = tid; i4 < 64 * 24; i4 += 256) {
        int m = i4 / 24;
        int k4 = (i4 - m * 24) * 4;
        int gm = row0 + m;
        float4 ag = make_float4(0.f, 0.f, 0.f, 0.f);
        if (gm < NN) ag = *(const float4*)(agg + (size_t)gm * FIN + k4);
        float* dst = As + m * 97 + k4;
        dst[0] = ag.x; dst[1] = ag.y; dst[2] = ag.z; dst[3] = ag.w;
    }
    for (int i4 = tid; i4 < 96 * 32; i4 += 256) {
        int kb = i4 >> 5;
        int nb4 = (i4 & 31) * 4;
        *(float4*)(Bs + kb * 128 + nb4) =
            *(const float4*)(W1 + (size_t)kb * FHID + n0 + nb4);
    }
    __syncthreads();

    float acc[4][8];
    #pragma unroll
    for (int r = 0; r < 4; ++r)
        #pragma unroll
        for (int c = 0; c < 8; ++c) acc[r][c] = 0.f;

    #pragma unroll 4
    for (int k = 0; k < 96; ++k) {
        float a[4];
        a[0] = As[(ty*4+0)*97 + k];
        a[1] = As[(ty*4+1)*97 + k];
        a[2] = As[(ty*4+2)*97 + k];
        a[3] = As[(ty*4+3)*97 + k];
        float4 bA = *(const float4*)(Bs + k*128 + tx*4);
        float4 bB = *(const float4*)(Bs + k*128 + 64 + tx*4);
        float b[8] = {bA.x,bA.y,bA.z,bA.w,bB.x,bB.y,bB.z,bB.w};
        #pragma unroll
        for (int r = 0; r < 4; ++r)
            #pragma unroll
            for (int c = 0; c < 8; ++c)
                acc[r][c] = fmaf(a[r], b[c], acc[r][c]);
    }

    float4 bb0 = *(const float4*)(b1 + n0 + tx*4);
    float4 bb1 = *(const float4*)(b1 + n0 + 64 + tx*4);
    float bv[8] = {bb0.x,bb0.y,bb0.z,bb0.w,bb1.x,bb1.y,bb1.z,bb1.w};
    float cs[8], cq[8];
    #pragma unroll
    for (int c = 0; c < 8; ++c) { cs[c] = 0.f; cq[c] = 0.f; }
    #pragma unroll
    for (int r = 0; r < 4; ++r) {
        int gm = row0 + ty*4 + r;
        if (gm < NN) {
            float v[8];
            #pragma unroll
            for (int c = 0; c < 8; ++c) {
                v[c] = acc[r][c] + bv[c];
                cs[c] += v[c];
                cq[c] += v[c]*v[c];
            }
            float* o = h1 + (size_t)gm * FHID + n0;
            *(float4*)(o + tx*4)      = make_float4(v[0],v[1],v[2],v[3]);
            *(float4*)(o + 64 + tx*4) = make_float4(v[4],v[5],v[6],v[7]);
        }
    }
    __syncthreads();
    #pragma unroll
    for (int j = 0; j < 4; ++j) {
        As[ty*128 + tx*4 + j]        = cs[j];
        As[ty*128 + 64 + tx*4 + j]   = cs[4+j];
        As[2048 + ty*128 + tx*4 + j]      = cq[j];
        As[2048 + ty*128 + 64 + tx*4 + j] = cq[4+j];
    }
    __syncthreads();
    if (tid < 128) {
        float s = 0.f;
        #pragma unroll
        for (int t = 0; t < 16; ++t) s += As[t*128 + tid];
        atomicAdd(sum1 + n0 + tid, s);
    } else {
        int c = tid - 128;
        float q = 0.f;
        #pragma unroll
        for (int t = 0; t < 16; ++t) q += As[2048 + t*128 + c];
        atomicAdd(sq1 + n0 + c, q);
    }
}

// ---- fold BN stats into scale/shift: y = scale*h + shift -----------------
__global__ __launch_bounds__(256) void bnparam_kernel(
    const float* __restrict__ sum, const float* __restrict__ sq,
    const float* __restrict__ g, const float* __restrict__ be,
    float* __restrict__ scale, float* __restrict__ shift, int F)
{
    int i = blockIdx.x * 256 + threadIdx.x;
    if (i >= F) return;
    float mean = sum[i] * (1.f / NN);
    float var  = sq[i] * (1.f / NN) - mean * mean;
    float s = g[i] * rsqrtf(var + BN_EPS);
    scale[i] = s;
    shift[i] = be[i] - mean * s;
}

// ---------------- GEMM2: out_pre = elu(bn1(h1)) @ W2 + b2, + stats2 ------
// full-N tile 64x192 (h1 read exactly once), K tiled by 32, acc 4x12.
__global__ __launch_bounds__(256) void gemm2_kernel(
    const float* __restrict__ h1, const float* __restrict__ W2,
    const float* __restrict__ b2,
    const float* __restrict__ scale1, const float* __restrict__ shift1,
    float* __restrict__ out, float* __restrict__ sum2, float* __restrict__ sq2)
{
    __shared__ float As[64 * 33];   // 8448 floats
    __shared__ float Bs[32 * 192];  // 6144 floats; reused for stats (2x3072)
    int tid = threadIdx.x;
    int tx = tid & 15, ty = tid >> 4;
    int row0 = blockIdx.x * 64;

    float acc[4][12];
    #pragma unroll
    for (int r = 0; r < 4; ++r)
        #pragma unroll
        for (int c = 0; c < 12; ++c) acc[r][c] = 0.f;

    for (int k0 = 0; k0 < FHID; k0 += 32) {
        // A tile with BN1 (precomputed scale/shift) + ELU
        #pragma unroll
        for (int l = 0; l < 2; ++l) {
            int i4 = tid + l * 256;
            int m = i4 >> 3;
            int kk4 = (i4 & 7) * 4;
            int gm = row0 + m;
            float av[4] = {0.f, 0.f, 0.f, 0.f};
            if (gm < NN) {
                float4 h = *(const float4*)(h1 + (size_t)gm * FHID + k0 + kk4);
                float hv[4] = {h.x, h.y, h.z, h.w};
                #pragma unroll
                for (int j = 0; j < 4; ++j) {
                    int k = k0 + kk4 + j;
                    float t = scale1[k] * hv[j] + shift1[k];
                    av[j] = t > 0.f ? t : expf(t) - 1.f;
                }
            }
            float* dst = As + m*33 + kk4;
            dst[0]=av[0]; dst[1]=av[1]; dst[2]=av[2]; dst[3]=av[3];
        }
        // B tile 32x192
        #pragma unroll
        for (int l = 0; l < 6; ++l) {
            int i4 = tid + l * 256;
            int kb = i4 / 48;
            int nb4 = (i4 - kb * 48) * 4;
            *(float4*)(Bs + kb*192 + nb4) =
                *(const float4*)(W2 + (size_t)(k0+kb) * FOUT + nb4);
        }
        __syncthreads();
        #pragma unroll 8
        for (int kk = 0; kk < 32; ++kk) {
            float a[4];
            a[0] = As[(ty*4+0)*33 + kk];
            a[1] = As[(ty*4+1)*33 + kk];
            a[2] = As[(ty*4+2)*33 + kk];
            a[3] = As[(ty*4+3)*33 + kk];
            float4 b0 = *(const float4*)(Bs + kk*192 + tx*4);
            float4 b1v = *(const float4*)(Bs + kk*192 + 64 + tx*4);
            float4 b2v = *(const float4*)(Bs + kk*192 + 128 + tx*4);
            float b[12] = {b0.x,b0.y,b0.z,b0.w, b1v.x,b1v.y,b1v.z,b1v.w,
                           b2v.x,b2v.y,b2v.z,b2v.w};
            #pragma unroll
            for (int r = 0; r < 4; ++r)
                #pragma unroll
                for (int c = 0; c < 12; ++c)
                    acc[r][c] = fmaf(a[r], b[c], acc[r][c]);
        }
        __syncthreads();
    }

    // epilogue: bias, store pre-activation, per-column stats
    float4 bb0 = *(const float4*)(b2 + tx*4);
    float4 bb1 = *(const float4*)(b2 + 64 + tx*4);
    float4 bb2 = *(const float4*)(b2 + 128 + tx*4);
    float bv[12] = {bb0.x,bb0.y,bb0.z,bb0.w, bb1.x,bb1.y,bb1.z,bb1.w,
                    bb2.x,bb2.y,bb2.z,bb2.w};
    float cs[12], cq[12];
    #pragma unroll
    for (int c = 0; c < 12; ++c) { cs[c] = 0.f; cq[c] = 0.f; }
    #pragma unroll
    for (int r = 0; r < 4; ++r) {
        int gm = row0 + ty*4 + r;
        if (gm < NN) {
            float v[12];
            #pragma unroll
            for (int c = 0; c < 12; ++c) {
                v[c] = acc[r][c] + bv[c];
                cs[c] += v[c];
                cq[c] += v[c]*v[c];
            }
            float* o = out + (size_t)gm * FOUT;
            *(float4*)(o + tx*4)       = make_float4(v[0],v[1],v[2],v[3]);
            *(float4*)(o + 64 + tx*4)  = make_float4(v[4],v[5],v[6],v[7]);
            *(float4*)(o + 128 + tx*4) = make_float4(v[8],v[9],v[10],v[11]);
        }
    }
    // Bs reads all done (loop ended with __syncthreads); reuse for stats
    #pragma unroll
    for (int j = 0; j < 12; ++j) {
        int colj = (j >> 2) * 64 + tx * 4 + (j & 3);
        Bs[ty * 192 + colj]        = cs[j];
        Bs[3072 + ty * 192 + colj] = cq[j];
    }
    __syncthreads();
    if (tid < 192) {
        float s = 0.f, q = 0.f;
        #pragma unroll
        for (int t = 0; t < 16; ++t) {
            s += Bs[t*192 + tid];
            q += Bs[3072 + t*192 + tid];
        }
        atomicAdd(sum2 + tid, s);
        atomicAdd(sq2 + tid, q);
    }
}

// ---------------- BN2 + ELU, in-place on d_out ---------------------------
__global__ __launch_bounds__(256) void bn2_elu_kernel(
    float* __restrict__ out, const float* __restrict__ scale2,
    const float* __restrict__ shift2)
{
    int gid = blockIdx.x * 256 + threadIdx.x;
    if (gid >= NN * FOUT / 4) return;
    size_t base = (size_t)gid * 4;
    int c0 = (int)(base % FOUT);
    float4 h = *(float4*)(out + base);
    float hv[4] = {h.x, h.y, h.z, h.w};
    float rv[4];
    #pragma unroll
    for (int j = 0; j < 4; ++j) {
        float t = scale2[c0 + j] * hv[j] + shift2[c0 + j];
        rv[j] = t > 0.f ? t : expf(t) - 1.f;
    }
    *(float4*)(out + base) = make_float4(rv[0], rv[1], rv[2], rv[3]);
}

__global__ __launch_bounds__(256) void zero_out_kernel(float* out, int n) {
    int gid = blockIdx.x * 256 + threadIdx.x;
    if (gid < n) out[gid] = 0.f;
}

extern "C" void kernel_launch(void* const* d_in, const int* in_sizes, int n_in,
                              void* d_out, int out_size, void* d_ws, size_t ws_size,
                              hipStream_t stream) {
    const float* x    = (const float*)d_in[0];
    const float* val  = (const float*)d_in[1];
    const float* W1   = (const float*)d_in[2];
    const float* b1   = (const float*)d_in[3];
    const float* g1   = (const float*)d_in[4];
    const float* be1  = (const float*)d_in[5];
    const float* W2   = (const float*)d_in[6];
    const float* b2   = (const float*)d_in[7];
    const float* g2   = (const float*)d_in[8];
    const float* be2  = (const float*)d_in[9];
    const float* epsp = (const float*)d_in[10];
    const int* row    = (const int*)d_in[11];
    const int* col    = (const int*)d_in[12];
    float* out = (float*)d_out;

    // ws layout (float idx):
    //      0: sum1[384] | 384: sq1[384] | 768: sum2[192] | 960: sq2[192]
    //   1152: scale1[384] | 1536: shift1[384] | 1920: scale2[192] | 2112: shift2[192]
    //   2304: deg/cursor int[50000]
    //  52304: offsets int[50001]
    // 102305: bsum int[256]  (pad to 102564)
    // 102564: agg float[4.8M]
    // 4902564: h1 float[19.2M]   (ecol int[800K] + eval float[800K] alias h1:
    //                             dead before gemm1 writes h1)
    const size_t need = (size_t)(4902564 + (size_t)NN * FHID) * sizeof(float);
    if (ws_size < need) {
        zero_out_kernel<<<(out_size + 255) / 256, 256, 0, stream>>>(out, out_size);
        return;
    }
    float* ws     = (float*)d_ws;
    float* sum1   = ws;
    float* sq1    = ws + 384;
    float* sum2   = ws + 768;
    float* sq2    = ws + 960;
    float* scale1 = ws + 1152;
    float* shift1 = ws + 1536;
    float* scale2 = ws + 1920;
    float* shift2 = ws + 2112;
    int*   deg    = (int*)(ws + 2304);      // becomes cursor after scan_final
    int*   offs   = (int*)(ws + 52304);
    int*   bsum   = (int*)(ws + 102305);
    float* agg    = ws + 102564;
    float* h1     = ws + 4902564;
    int*   ecol   = (int*)h1;               // alias: dead before h1 written
    float* eval   = h1 + EE;

    // zero stats + deg (209 KB)
    hipMemsetAsync(d_ws, 0, 52304 * sizeof(float), stream);

    hist_kernel<<<(EE + 255) / 256, 256, 0, stream>>>(row, deg);
    scan_partial_kernel<<<NBLK_SCAN, 256, 0, stream>>>(deg, bsum);
    scan_tot_kernel<<<1, 256, 0, stream>>>(bsum, offs);
    scan_final_kernel<<<NBLK_SCAN, 256, 0, stream>>>(deg, bsum, offs);
    scatter_kernel<<<(EE + 255) / 256, 256, 0, stream>>>(row, col, val, deg,
                                                         ecol, eval);
    gather_kernel<<<(NN + 7) / 8, 256, 0, stream>>>(x, offs, ecol, eval,
                                                    epsp, agg);

    dim3 grid1((NN + 63) / 64, 3, 1);
    gemm1_kernel<<<grid1, 256, 0, stream>>>(agg, W1, b1, h1, sum1, sq1);
    bnparam_kernel<<<2, 256, 0, stream>>>(sum1, sq1, g1, be1, scale1, shift1, FHID);

    gemm2_kernel<<<(NN + 63) / 64, 256, 0, stream>>>(h1, W2, b2, scale1, shift1,
                                                     out, sum2, sq2);
    bnparam_kernel<<<1, 256, 0, stream>>>(sum2, sq2, g2, be2, scale2, shift2, FOUT);

    bn2_elu_kernel<<<(NN * FOUT / 4 + 255) / 256, 256, 0, stream>>>(
        out, scale2, shift2);
}

// Round 4
// 355.189 us; speedup vs baseline: 1.6610x; 1.3099x over previous
//
#include <hip/hip_runtime.h>
#include <math.h>

#define NN 50000
#define EE 800000
#define FIN 96
#define FHID 384
#define FOUT 192
#define BN_EPS 1e-5f
#define NBLK_SCAN 196   // ceil(NN/256)

typedef short  short4v  __attribute__((ext_vector_type(4)));
typedef short  short8v  __attribute__((ext_vector_type(8)));
typedef float  f32x4    __attribute__((ext_vector_type(4)));

__device__ __forceinline__ unsigned short f2b(float f) {   // fp32 -> bf16 RNE
    unsigned u = __float_as_uint(f);
    unsigned r = u + 0x7FFFu + ((u >> 16) & 1u);
    return (unsigned short)(r >> 16);
}
__device__ __forceinline__ float b2f(unsigned short s) {
    return __uint_as_float((unsigned)s << 16);
}

// ---------------- CSR build ----------------
__global__ __launch_bounds__(256) void hist_kernel(
    const int* __restrict__ row, int* __restrict__ deg)
{
    int i = blockIdx.x * 256 + threadIdx.x;
    if (i < EE) atomicAdd(&deg[row[i]], 1);
}

__global__ __launch_bounds__(256) void scan_partial_kernel(
    const int* __restrict__ deg, int* __restrict__ bsum)
{
    __shared__ int s[256];
    int t = threadIdx.x;
    int i = blockIdx.x * 256 + t;
    s[t] = (i < NN) ? deg[i] : 0;
    __syncthreads();
    #pragma unroll
    for (int o = 128; o > 0; o >>= 1) {
        if (t < o) s[t] += s[t + o];
        __syncthreads();
    }
    if (t == 0) bsum[blockIdx.x] = s[0];
}

__global__ __launch_bounds__(256) void scan_tot_kernel(
    int* __restrict__ bsum, int* __restrict__ offsets)
{
    __shared__ int s[256];
    int t = threadIdx.x;
    int v = (t < NBLK_SCAN) ? bsum[t] : 0;
    s[t] = v;
    __syncthreads();
    for (int o = 1; o < 256; o <<= 1) {
        int add = (t >= o) ? s[t - o] : 0;
        __syncthreads();
        s[t] += add;
        __syncthreads();
    }
    if (t < NBLK_SCAN) bsum[t] = s[t] - v;
    if (t == 255) offsets[NN] = s[255];
}

__global__ __launch_bounds__(256) void scan_final_kernel(
    int* deg_and_cursor, const int* __restrict__ bsum, int* __restrict__ offsets)
{
    __shared__ int s[256];
    int t = threadIdx.x;
    int i = blockIdx.x * 256 + t;
    int v = (i < NN) ? deg_and_cursor[i] : 0;
    s[t] = v;
    __syncthreads();
    for (int o = 1; o < 256; o <<= 1) {
        int add = (t >= o) ? s[t - o] : 0;
        __syncthreads();
        s[t] += add;
        __syncthreads();
    }
    int excl = s[t] - v + bsum[blockIdx.x];
    if (i < NN) {
        offsets[i] = excl;
        deg_and_cursor[i] = excl;
    }
}

__global__ __launch_bounds__(256) void scatter_kernel(
    const int* __restrict__ row, const int* __restrict__ col,
    const float* __restrict__ val, int* cursor,
    int* __restrict__ ecol, float* __restrict__ eval)
{
    int i = blockIdx.x * 256 + threadIdx.x;
    if (i >= EE) return;
    int r = row[i];
    int p = atomicAdd(&cursor[r], 1);
    ecol[p] = col[i];
    eval[p] = val[i];
}

// ---------------- gather-aggregate (fp32) --------------------------------
__global__ __launch_bounds__(256) void gather_kernel(
    const float* __restrict__ x, const int* __restrict__ offsets,
    const int* __restrict__ ecol, const float* __restrict__ eval,
    const float* __restrict__ epsp, float* __restrict__ agg)
{
    int rid = blockIdx.x * 8 + (threadIdx.x >> 5);
    if (rid >= NN) return;
    int lane = threadIdx.x & 31;
    int beg = offsets[rid], end = offsets[rid + 1];
    float a0 = 0.f, a1 = 0.f, a2 = 0.f;
    for (int j = beg; j < end; ++j) {
        int c = ecol[j];
        float v = eval[j];
        const float* xr = x + (size_t)c * FIN;
        a0 += v * xr[lane];
        a1 += v * xr[lane + 32];
        a2 += v * xr[lane + 64];
    }
    float e = epsp[0];
    const float* xs = x + (size_t)rid * FIN;
    a0 += e * xs[lane];
    a1 += e * xs[lane + 32];
    a2 += e * xs[lane + 64];
    float* ar = agg + (size_t)rid * FIN;
    ar[lane] = a0; ar[lane + 32] = a1; ar[lane + 64] = a2;
}

// ---------------- weight prep: bf16 + transpose to [n][k] ----------------
__global__ __launch_bounds__(256) void prep_w_kernel(
    const float* __restrict__ W1, const float* __restrict__ W2,
    unsigned short* __restrict__ W1T, unsigned short* __restrict__ W2T)
{
    int i = blockIdx.x * 256 + threadIdx.x;
    if (i < FHID * FIN) {                   // W1T[n][k] = W1[k][n]
        int n = i / FIN, k = i - n * FIN;
        W1T[i] = f2b(W1[(size_t)k * FHID + n]);
    }
    int j = i - FHID * FIN;
    if (j >= 0 && j < FOUT * FHID) {        // W2T[n][k] = W2[k][n]
        int n = j / FHID, k = j - n * FHID;
        W2T[j] = f2b(W2[(size_t)k * FOUT + n]);
    }
}

// ---------------- GEMM1 (MFMA): h1 = agg @ W1 + b1, bf16 out + stats -----
// BM=128, BN=128, K=96 resident. 4 waves, wave tile 64x64 (4x4 frags).
__global__ __launch_bounds__(256) void gemm1_mfma_kernel(
    const float* __restrict__ agg, const unsigned short* __restrict__ W1T,
    const float* __restrict__ b1,
    unsigned short* __restrict__ h1, float* __restrict__ sum1,
    float* __restrict__ sq1)
{
    __shared__ short As[128 * 104];   // [m][k] bf16, stride 104
    __shared__ short Bs[128 * 104];   // [n][k] bf16, stride 104
    int tid = threadIdx.x;
    int m0 = blockIdx.x * 128;
    int n0 = blockIdx.y * 128;
    int lane = tid & 63;
    int w = tid >> 6, wr = w >> 1, wc = w & 1;
    int l15 = lane & 15, lk = (lane >> 4) * 8;

    // stage A: agg fp32 -> bf16, 128 rows x 96 k
    for (int i4 = tid; i4 < 128 * 24; i4 += 256) {
        int m = i4 / 24;
        int k4 = (i4 - m * 24) * 4;
        int gm = m0 + m;
        float4 a = make_float4(0.f, 0.f, 0.f, 0.f);
        if (gm < NN) a = *(const float4*)(agg + (size_t)gm * FIN + k4);
        short4v s; s.x = f2b(a.x); s.y = f2b(a.y); s.z = f2b(a.z); s.w = f2b(a.w);
        *(short4v*)&As[m * 104 + k4] = s;
    }
    // stage B: W1T rows n0..n0+127, 96 k, vec8 copies
    for (int i8 = tid; i8 < 128 * 12; i8 += 256) {
        int n = i8 / 12;
        int k8 = (i8 - n * 12) * 8;
        *(short8v*)&Bs[n * 104 + k8] =
            *(const short8v*)(W1T + (size_t)(n0 + n) * FIN + k8);
    }
    __syncthreads();

    f32x4 acc[4][4];
    #pragma unroll
    for (int a = 0; a < 4; ++a)
        #pragma unroll
        for (int b = 0; b < 4; ++b) acc[a][b] = (f32x4)(0.f);

    #pragma unroll
    for (int ks = 0; ks < 3; ++ks) {
        int k0 = ks * 32;
        short8v af[4], bf[4];
        #pragma unroll
        for (int f = 0; f < 4; ++f)
            af[f] = *(short8v*)&As[(wr*64 + f*16 + l15) * 104 + k0 + lk];
        #pragma unroll
        for (int f = 0; f < 4; ++f)
            bf[f] = *(short8v*)&Bs[(wc*64 + f*16 + l15) * 104 + k0 + lk];
        #pragma unroll
        for (int fm = 0; fm < 4; ++fm)
            #pragma unroll
            for (int fn = 0; fn < 4; ++fn)
                acc[fm][fn] = __builtin_amdgcn_mfma_f32_16x16x32_bf16(
                    af[fm], bf[fn], acc[fm][fn], 0, 0, 0);
    }

    // epilogue: bias, bf16 h1 store, column stats
    float bias[4], cs[4], cq[4];
    #pragma unroll
    for (int fn = 0; fn < 4; ++fn) {
        bias[fn] = b1[n0 + wc*64 + fn*16 + l15];
        cs[fn] = 0.f; cq[fn] = 0.f;
    }
    #pragma unroll
    for (int fm = 0; fm < 4; ++fm) {
        int mb = m0 + wr*64 + fm*16 + (lane >> 4) * 4;
        #pragma unroll
        for (int r = 0; r < 4; ++r) {
            int gm = mb + r;
            if (gm < NN) {
                #pragma unroll
                for (int fn = 0; fn < 4; ++fn) {
                    float h = acc[fm][fn][r] + bias[fn];
                    cs[fn] += h; cq[fn] += h * h;
                    h1[(size_t)gm * FHID + n0 + wc*64 + fn*16 + l15] = f2b(h);
                }
            }
        }
    }
    // reduce stats: across the 4 lane-groups sharing l15, then across waves
    #pragma unroll
    for (int fn = 0; fn < 4; ++fn) {
        cs[fn] += __shfl_xor(cs[fn], 16); cs[fn] += __shfl_xor(cs[fn], 32);
        cq[fn] += __shfl_xor(cq[fn], 16); cq[fn] += __shfl_xor(cq[fn], 32);
    }
    __syncthreads();                 // all LDS k-reads done; reuse As
    float* sS = (float*)As;          // [4 waves][64] sum, then [4][64] sq
    if (lane < 16) {
        #pragma unroll
        for (int fn = 0; fn < 4; ++fn) {
            sS[w * 64 + fn * 16 + l15]       = cs[fn];
            sS[256 + w * 64 + fn * 16 + l15] = cq[fn];
        }
    }
    __syncthreads();
    if (tid < 128) {   // n_local = tid; waves wc and 2+wc hold its partials
        float s = sS[tid] + sS[tid + 128];
        float q = sS[256 + tid] + sS[256 + tid + 128];
        atomicAdd(sum1 + n0 + tid, s);
        atomicAdd(sq1 + n0 + tid, q);
    }
}

// ---- fold BN stats into scale/shift --------------------------------------
__global__ __launch_bounds__(256) void bnparam_kernel(
    const float* __restrict__ sum, const float* __restrict__ sq,
    const float* __restrict__ g, const float* __restrict__ be,
    float* __restrict__ scale, float* __restrict__ shift, int F)
{
    int i = blockIdx.x * 256 + threadIdx.x;
    if (i >= F) return;
    float mean = sum[i] * (1.f / NN);
    float var  = sq[i] * (1.f / NN) - mean * mean;
    float s = g[i] * rsqrtf(var + BN_EPS);
    scale[i] = s;
    shift[i] = be[i] - mean * s;
}

// ---------------- GEMM2 (MFMA): out = elu(bn1(h1)) @ W2 + b2, + stats ----
// BM=64, BN=192 (full N), BK=32 x 12 stages. 4 waves, wave tile 32x96.
__global__ __launch_bounds__(256) void gemm2_mfma_kernel(
    const unsigned short* __restrict__ h1, const unsigned short* __restrict__ W2T,
    const float* __restrict__ b2,
    const float* __restrict__ scale1, const float* __restrict__ shift1,
    float* __restrict__ out, float* __restrict__ sum2, float* __restrict__ sq2)
{
    __shared__ short As[64 * 40];    // [m][kk] bf16
    __shared__ short Bs[192 * 40];   // [n][kk] bf16
    __shared__ float sc[FHID], sh[FHID];
    int tid = threadIdx.x;
    int m0 = blockIdx.x * 64;
    int lane = tid & 63;
    int w = tid >> 6, wr = w >> 1, wc = w & 1;
    int l15 = lane & 15, lk = (lane >> 4) * 8;

    for (int i = tid; i < FHID; i += 256) { sc[i] = scale1[i]; sh[i] = shift1[i]; }
    __syncthreads();

    f32x4 acc[2][6];
    #pragma unroll
    for (int a = 0; a < 2; ++a)
        #pragma unroll
        for (int b = 0; b < 6; ++b) acc[a][b] = (f32x4)(0.f);

    for (int k0 = 0; k0 < FHID; k0 += 32) {
        // stage A: h1 bf16 -> bn1 -> elu -> bf16 (64 rows x 32 k = 256 vec8)
        {
            int m = tid >> 2;
            int k8 = (tid & 3) * 8;
            int gm = m0 + m;
            short8v v = (short8v)(short)0;
            if (gm < NN) {
                short8v hv = *(const short8v*)(h1 + (size_t)gm * FHID + k0 + k8);
                #pragma unroll
                for (int j = 0; j < 8; ++j) {
                    int k = k0 + k8 + j;
                    float t = sc[k] * b2f((unsigned short)hv[j]) + sh[k];
                    float e = t > 0.f ? t : __expf(t) - 1.f;
                    v[j] = (short)f2b(e);
                }
            }
            *(short8v*)&As[m * 40 + k8] = v;
        }
        // stage B: W2T rows 0..191, k-slice (192 x 32 = 768 vec8)
        #pragma unroll
        for (int l = 0; l < 3; ++l) {
            int i8 = tid + l * 256;
            int n = i8 >> 2;
            int k8 = (i8 & 3) * 8;
            *(short8v*)&Bs[n * 40 + k8] =
                *(const short8v*)(W2T + (size_t)n * FHID + k0 + k8);
        }
        __syncthreads();

        short8v af[2], bf[6];
        #pragma unroll
        for (int f = 0; f < 2; ++f)
            af[f] = *(short8v*)&As[(wr*32 + f*16 + l15) * 40 + lk];
        #pragma unroll
        for (int f = 0; f < 6; ++f)
            bf[f] = *(short8v*)&Bs[(wc*96 + f*16 + l15) * 40 + lk];
        #pragma unroll
        for (int fm = 0; fm < 2; ++fm)
            #pragma unroll
            for (int fn = 0; fn < 6; ++fn)
                acc[fm][fn] = __builtin_amdgcn_mfma_f32_16x16x32_bf16(
                    af[fm], bf[fn], acc[fm][fn], 0, 0, 0);
        __syncthreads();
    }

    // epilogue: bias, fp32 store (pre-BN2), column stats
    float bias[6], cs[6], cq[6];
    #pragma unroll
    for (int fn = 0; fn < 6; ++fn) {
        bias[fn] = b2[wc*96 + fn*16 + l15];
        cs[fn] = 0.f; cq[fn] = 0.f;
    }
    #pragma unroll
    for (int fm = 0; fm < 2; ++fm) {
        int mb = m0 + wr*32 + fm*16 + (lane >> 4) * 4;
        #pragma unroll
        for (int r = 0; r < 4; ++r) {
            int gm = mb + r;
            if (gm < NN) {
                #pragma unroll
                for (int fn = 0; fn < 6; ++fn) {
                    float v = acc[fm][fn][r] + bias[fn];
                    cs[fn] += v; cq[fn] += v * v;
                    out[(size_t)gm * FOUT + wc*96 + fn*16 + l15] = v;
                }
            }
        }
    }
    #pragma unroll
    for (int fn = 0; fn < 6; ++fn) {
        cs[fn] += __shfl_xor(cs[fn], 16); cs[fn] += __shfl_xor(cs[fn], 32);
        cq[fn] += __shfl_xor(cq[fn], 16); cq[fn] += __shfl_xor(cq[fn], 32);
    }
    __syncthreads();                // loop ended with sync; safe to reuse As
    float* sS = (float*)As;         // [4][96] sum then [4][96] sq (768 f)
    if (lane < 16) {
        #pragma unroll
        for (int fn = 0; fn < 6; ++fn) {
            sS[w * 96 + fn * 16 + l15]       = cs[fn];
            sS[384 + w * 96 + fn * 16 + l15] = cq[fn];
        }
    }
    __syncthreads();
    if (tid < 192) {   // n = tid; waves wc and 2+wc hold its partials
        float s = sS[tid] + sS[tid + 192];
        float q = sS[384 + tid] + sS[384 + tid + 192];
        atomicAdd(sum2 + tid, s);
        atomicAdd(sq2 + tid, q);
    }
}

// ---------------- BN2 + ELU, in-place ------------------------------------
__global__ __launch_bounds__(256) void bn2_elu_kernel(
    float* __restrict__ out, const float* __restrict__ scale2,
    const float* __restrict__ shift2)
{
    int gid = blockIdx.x * 256 + threadIdx.x;
    if (gid >= NN * FOUT / 4) return;
    size_t base = (size_t)gid * 4;
    int c0 = (int)(base % FOUT);
    float4 h = *(float4*)(out + base);
    float hv[4] = {h.x, h.y, h.z, h.w};
    float rv[4];
    #pragma unroll
    for (int j = 0; j < 4; ++j) {
        float t = scale2[c0 + j] * hv[j] + shift2[c0 + j];
        rv[j] = t > 0.f ? t : __expf(t) - 1.f;
    }
    *(float4*)(out + base) = make_float4(rv[0], rv[1], rv[2], rv[3]);
}

__global__ __launch_bounds__(256) void zero_out_kernel(float* out, int n) {
    int gid = blockIdx.x * 256 + threadIdx.x;
    if (gid < n) out[gid] = 0.f;
}

extern "C" void kernel_launch(void* const* d_in, const int* in_sizes, int n_in,
                              void* d_out, int out_size, void* d_ws, size_t ws_size,
                              hipStream_t stream) {
    const float* x    = (const float*)d_in[0];
    const float* val  = (const float*)d_in[1];
    const float* W1   = (const float*)d_in[2];
    const float* b1   = (const float*)d_in[3];
    const float* g1   = (const float*)d_in[4];
    const float* be1  = (const float*)d_in[5];
    const float* W2   = (const float*)d_in[6];
    const float* b2   = (const float*)d_in[7];
    const float* g2   = (const float*)d_in[8];
    const float* be2  = (const float*)d_in[9];
    const float* epsp = (const float*)d_in[10];
    const int* row    = (const int*)d_in[11];
    const int* col    = (const int*)d_in[12];
    float* out = (float*)d_out;

    // ws layout (float idx):
    //      0 sum1[384] | 384 sq1[384] | 768 sum2[192] | 960 sq2[192]
    //   1152 scale1[384] | 1536 shift1[384] | 1920 scale2[192] | 2112 shift2[192]
    //   2304 deg/cursor int[50000] | 52304 offs int[50001] | 102305 bsum[256]
    // 102564 W1T ushort[36864] (18432 f)
    // 120996 W2T ushort[73728] (36864 f)
    // 157860 agg f32[4.8M]
    // 4957860 h1 bf16[19.2M] (9.6M f)   (ecol/eval alias h1: dead before gemm1)
    const size_t need = (size_t)(4957860 + 9600000) * sizeof(float);
    if (ws_size < need) {
        zero_out_kernel<<<(out_size + 255) / 256, 256, 0, stream>>>(out, out_size);
        return;
    }
    float* ws     = (float*)d_ws;
    float* sum1   = ws;
    float* sq1    = ws + 384;
    float* sum2   = ws + 768;
    float* sq2    = ws + 960;
    float* scale1 = ws + 1152;
    float* shift1 = ws + 1536;
    float* scale2 = ws + 1920;
    float* shift2 = ws + 2112;
    int*   deg    = (int*)(ws + 2304);
    int*   offs   = (int*)(ws + 52304);
    int*   bsum   = (int*)(ws + 102305);
    unsigned short* W1T = (unsigned short*)(ws + 102564);
    unsigned short* W2T = (unsigned short*)(ws + 120996);
    float* agg    = ws + 157860;
    unsigned short* h1 = (unsigned short*)(ws + 4957860);
    int*   ecol   = (int*)(ws + 4957860);          // alias h1 (dead early)
    float* eval   = (float*)(ws + 4957860) + EE;

    hipMemsetAsync(d_ws, 0, 52304 * sizeof(float), stream);   // stats + deg

    prep_w_kernel<<<(FHID*FIN + FOUT*FHID + 255) / 256, 256, 0, stream>>>(
        W1, W2, W1T, W2T);

    hist_kernel<<<(EE + 255) / 256, 256, 0, stream>>>(row, deg);
    scan_partial_kernel<<<NBLK_SCAN, 256, 0, stream>>>(deg, bsum);
    scan_tot_kernel<<<1, 256, 0, stream>>>(bsum, offs);
    scan_final_kernel<<<NBLK_SCAN, 256, 0, stream>>>(deg, bsum, offs);
    scatter_kernel<<<(EE + 255) / 256, 256, 0, stream>>>(row, col, val, deg,
                                                         ecol, eval);
    gather_kernel<<<(NN + 7) / 8, 256, 0, stream>>>(x, offs, ecol, eval,
                                                    epsp, agg);

    dim3 grid1((NN + 127) / 128, 3, 1);
    gemm1_mfma_kernel<<<grid1, 256, 0, stream>>>(agg, W1T, b1, h1, sum1, sq1);
    bnparam_kernel<<<2, 256, 0, stream>>>(sum1, sq1, g1, be1, scale1, shift1, FHID);

    gemm2_mfma_kernel<<<(NN + 63) / 64, 256, 0, stream>>>(
        h1, W2T, b2, scale1, shift1, out, sum2, sq2);
    bnparam_kernel<<<1, 256, 0, stream>>>(sum2, sq2, g2, be2, scale2, shift2, FOUT);

    bn2_elu_kernel<<<(NN * FOUT / 4 + 255) / 256, 256, 0, stream>>>(
        out, scale2, shift2);
}

// Round 5
// 320.120 us; speedup vs baseline: 1.8430x; 1.1096x over previous
//
#include <hip/hip_runtime.h>
#include <math.h>

#define NN 50000
#define EE 800000
#define FIN 96
#define FHID 384
#define FOUT 192
#define BN_EPS 1e-5f
#define NBLK_SCAN 196   // ceil(NN/256)

typedef short  short8v  __attribute__((ext_vector_type(8)));
typedef float  f32x4    __attribute__((ext_vector_type(4)));

__device__ __forceinline__ unsigned short f2b(float f) {   // fp32 -> bf16 RNE
    unsigned u = __float_as_uint(f);
    unsigned r = u + 0x7FFFu + ((u >> 16) & 1u);
    return (unsigned short)(r >> 16);
}
__device__ __forceinline__ float b2f(unsigned short s) {
    return __uint_as_float((unsigned)s << 16);
}

// ---------------- CSR build ----------------
__global__ __launch_bounds__(256) void hist_kernel(
    const int* __restrict__ row, int* __restrict__ deg)
{
    int i = blockIdx.x * 256 + threadIdx.x;
    if (i < EE) atomicAdd(&deg[row[i]], 1);
}

__global__ __launch_bounds__(256) void scan_partial_kernel(
    const int* __restrict__ deg, int* __restrict__ bsum)
{
    __shared__ int s[256];
    int t = threadIdx.x;
    int i = blockIdx.x * 256 + t;
    s[t] = (i < NN) ? deg[i] : 0;
    __syncthreads();
    #pragma unroll
    for (int o = 128; o > 0; o >>= 1) {
        if (t < o) s[t] += s[t + o];
        __syncthreads();
    }
    if (t == 0) bsum[blockIdx.x] = s[0];
}

__global__ __launch_bounds__(256) void scan_tot_kernel(
    int* __restrict__ bsum, int* __restrict__ offsets)
{
    __shared__ int s[256];
    int t = threadIdx.x;
    int v = (t < NBLK_SCAN) ? bsum[t] : 0;
    s[t] = v;
    __syncthreads();
    for (int o = 1; o < 256; o <<= 1) {
        int add = (t >= o) ? s[t - o] : 0;
        __syncthreads();
        s[t] += add;
        __syncthreads();
    }
    if (t < NBLK_SCAN) bsum[t] = s[t] - v;
    if (t == 255) offsets[NN] = s[255];
}

__global__ __launch_bounds__(256) void scan_final_kernel(
    int* deg_and_cursor, const int* __restrict__ bsum, int* __restrict__ offsets)
{
    __shared__ int s[256];
    int t = threadIdx.x;
    int i = blockIdx.x * 256 + t;
    int v = (i < NN) ? deg_and_cursor[i] : 0;
    s[t] = v;
    __syncthreads();
    for (int o = 1; o < 256; o <<= 1) {
        int add = (t >= o) ? s[t - o] : 0;
        __syncthreads();
        s[t] += add;
        __syncthreads();
    }
    int excl = s[t] - v + bsum[blockIdx.x];
    if (i < NN) {
        offsets[i] = excl;
        deg_and_cursor[i] = excl;
    }
}

// scatter packed edge payloads (one 8B store per edge)
__global__ __launch_bounds__(256) void scatter_kernel(
    const int* __restrict__ row, const int* __restrict__ col,
    const float* __restrict__ val, int* cursor, int2* __restrict__ epack)
{
    int i = blockIdx.x * 256 + threadIdx.x;
    if (i >= EE) return;
    int r = row[i];
    int p = atomicAdd(&cursor[r], 1);
    epack[p] = make_int2(col[i], __float_as_int(val[i]));
}

// ---------------- gather-aggregate -> bf16 agg ----------------------------
// 32 lanes/row, 3 floats/lane, 4-edge unroll for memory-level parallelism.
__global__ __launch_bounds__(256) void gather_kernel(
    const float* __restrict__ x, const int* __restrict__ offsets,
    const int2* __restrict__ epack, const float* __restrict__ epsp,
    unsigned short* __restrict__ aggb)
{
    int rid = blockIdx.x * 8 + (threadIdx.x >> 5);
    if (rid >= NN) return;
    int lane = threadIdx.x & 31;
    int beg = offsets[rid], end = offsets[rid + 1];
    float a0 = 0.f, a1 = 0.f, a2 = 0.f;
    int j = beg;
    for (; j + 4 <= end; j += 4) {
        int2 e0 = epack[j],   e1 = epack[j+1];
        int2 e2 = epack[j+2], e3 = epack[j+3];
        const float* x0 = x + (size_t)e0.x * FIN;
        const float* x1 = x + (size_t)e1.x * FIN;
        const float* x2 = x + (size_t)e2.x * FIN;
        const float* x3 = x + (size_t)e3.x * FIN;
        float v0 = __int_as_float(e0.y), v1 = __int_as_float(e1.y);
        float v2 = __int_as_float(e2.y), v3 = __int_as_float(e3.y);
        a0 += v0*x0[lane]    + v1*x1[lane]    + v2*x2[lane]    + v3*x3[lane];
        a1 += v0*x0[lane+32] + v1*x1[lane+32] + v2*x2[lane+32] + v3*x3[lane+32];
        a2 += v0*x0[lane+64] + v1*x1[lane+64] + v2*x2[lane+64] + v3*x3[lane+64];
    }
    for (; j < end; ++j) {
        int2 e = epack[j];
        float v = __int_as_float(e.y);
        const float* xr = x + (size_t)e.x * FIN;
        a0 += v * xr[lane];
        a1 += v * xr[lane + 32];
        a2 += v * xr[lane + 64];
    }
    float e = epsp[0];
    const float* xs = x + (size_t)rid * FIN;
    a0 += e * xs[lane];
    a1 += e * xs[lane + 32];
    a2 += e * xs[lane + 64];
    unsigned short* ar = aggb + (size_t)rid * FIN;
    ar[lane]      = f2b(a0);
    ar[lane + 32] = f2b(a1);
    ar[lane + 64] = f2b(a2);
}

// ---------------- weight prep: bf16 + transpose to [n][k] ----------------
__global__ __launch_bounds__(256) void prep_w_kernel(
    const float* __restrict__ W1, const float* __restrict__ W2,
    unsigned short* __restrict__ W1T, unsigned short* __restrict__ W2T)
{
    int i = blockIdx.x * 256 + threadIdx.x;
    if (i < FHID * FIN) {                   // W1T[n][k] = W1[k][n]
        int n = i / FIN, k = i - n * FIN;
        W1T[i] = f2b(W1[(size_t)k * FHID + n]);
    }
    int j = i - FHID * FIN;
    if (j >= 0 && j < FOUT * FHID) {        // W2T[n][k] = W2[k][n]
        int n = j / FHID, k = j - n * FHID;
        W2T[j] = f2b(W2[(size_t)k * FOUT + n]);
    }
}

// ---------------- GEMM1 (MFMA): h1 = agg @ W1 + b1, bf16 out + stats -----
// BM=128, BN=128, K=96 resident. 4 waves, wave tile 64x64 (4x4 frags).
__global__ __launch_bounds__(256) void gemm1_mfma_kernel(
    const unsigned short* __restrict__ aggb, const unsigned short* __restrict__ W1T,
    const float* __restrict__ b1,
    unsigned short* __restrict__ h1, float* __restrict__ sum1,
    float* __restrict__ sq1)
{
    __shared__ short As[128 * 104];   // [m][k] bf16
    __shared__ short Bs[128 * 104];   // [n][k] bf16
    int tid = threadIdx.x;
    int m0 = blockIdx.x * 128;
    int n0 = blockIdx.y * 128;
    int lane = tid & 63;
    int w = tid >> 6, wr = w >> 1, wc = w & 1;
    int l15 = lane & 15, lk = (lane >> 4) * 8;

    // stage A: aggb bf16, 128 rows x 96 k = 1536 vec8
    for (int i8 = tid; i8 < 128 * 12; i8 += 256) {
        int m = i8 / 12;
        int k8 = (i8 - m * 12) * 8;
        int gm = m0 + m;
        short8v v = (short8v)(short)0;
        if (gm < NN) v = *(const short8v*)(aggb + (size_t)gm * FIN + k8);
        *(short8v*)&As[m * 104 + k8] = v;
    }
    // stage B: W1T rows n0..n0+127
    for (int i8 = tid; i8 < 128 * 12; i8 += 256) {
        int n = i8 / 12;
        int k8 = (i8 - n * 12) * 8;
        *(short8v*)&Bs[n * 104 + k8] =
            *(const short8v*)(W1T + (size_t)(n0 + n) * FIN + k8);
    }
    __syncthreads();

    f32x4 acc[4][4];
    #pragma unroll
    for (int a = 0; a < 4; ++a)
        #pragma unroll
        for (int b = 0; b < 4; ++b) acc[a][b] = (f32x4)(0.f);

    #pragma unroll
    for (int ks = 0; ks < 3; ++ks) {
        int k0 = ks * 32;
        short8v af[4], bf[4];
        #pragma unroll
        for (int f = 0; f < 4; ++f)
            af[f] = *(short8v*)&As[(wr*64 + f*16 + l15) * 104 + k0 + lk];
        #pragma unroll
        for (int f = 0; f < 4; ++f)
            bf[f] = *(short8v*)&Bs[(wc*64 + f*16 + l15) * 104 + k0 + lk];
        #pragma unroll
        for (int fm = 0; fm < 4; ++fm)
            #pragma unroll
            for (int fn = 0; fn < 4; ++fn)
                acc[fm][fn] = __builtin_amdgcn_mfma_f32_16x16x32_bf16(
                    af[fm], bf[fn], acc[fm][fn], 0, 0, 0);
    }

    float bias[4], cs[4], cq[4];
    #pragma unroll
    for (int fn = 0; fn < 4; ++fn) {
        bias[fn] = b1[n0 + wc*64 + fn*16 + l15];
        cs[fn] = 0.f; cq[fn] = 0.f;
    }
    #pragma unroll
    for (int fm = 0; fm < 4; ++fm) {
        int mb = m0 + wr*64 + fm*16 + (lane >> 4) * 4;
        #pragma unroll
        for (int r = 0; r < 4; ++r) {
            int gm = mb + r;
            if (gm < NN) {
                #pragma unroll
                for (int fn = 0; fn < 4; ++fn) {
                    float h = acc[fm][fn][r] + bias[fn];
                    cs[fn] += h; cq[fn] += h * h;
                    h1[(size_t)gm * FHID + n0 + wc*64 + fn*16 + l15] = f2b(h);
                }
            }
        }
    }
    #pragma unroll
    for (int fn = 0; fn < 4; ++fn) {
        cs[fn] += __shfl_xor(cs[fn], 16); cs[fn] += __shfl_xor(cs[fn], 32);
        cq[fn] += __shfl_xor(cq[fn], 16); cq[fn] += __shfl_xor(cq[fn], 32);
    }
    __syncthreads();
    float* sS = (float*)As;          // [4 waves][64] sum, then [4][64] sq
    if (lane < 16) {
        #pragma unroll
        for (int fn = 0; fn < 4; ++fn) {
            sS[w * 64 + fn * 16 + l15]       = cs[fn];
            sS[256 + w * 64 + fn * 16 + l15] = cq[fn];
        }
    }
    __syncthreads();
    if (tid < 128) {
        float s = sS[tid] + sS[tid + 128];
        float q = sS[256 + tid] + sS[256 + tid + 128];
        atomicAdd(sum1 + n0 + tid, s);
        atomicAdd(sq1 + n0 + tid, q);
    }
}

// ---- fold BN stats into scale/shift --------------------------------------
__global__ __launch_bounds__(256) void bnparam_kernel(
    const float* __restrict__ sum, const float* __restrict__ sq,
    const float* __restrict__ g, const float* __restrict__ be,
    float* __restrict__ scale, float* __restrict__ shift, int F)
{
    int i = blockIdx.x * 256 + threadIdx.x;
    if (i >= F) return;
    float mean = sum[i] * (1.f / NN);
    float var  = sq[i] * (1.f / NN) - mean * mean;
    float s = g[i] * rsqrtf(var + BN_EPS);
    scale[i] = s;
    shift[i] = be[i] - mean * s;
}

// ---------------- GEMM2 (MFMA): out = elu(bn1(h1)) @ W2 + b2, + stats ----
// BM=64, BN=192(full), BK=64 x 6 phases, reg double-buffered staging.
// 4 waves, wave tile 32x96 (2x6 frags).
#define G2_LDA 72
#define G2_LDB 72
__global__ __launch_bounds__(256) void gemm2_mfma_kernel(
    const unsigned short* __restrict__ h1, const unsigned short* __restrict__ W2T,
    const float* __restrict__ b2,
    const float* __restrict__ scale1, const float* __restrict__ shift1,
    float* __restrict__ out, float* __restrict__ sum2, float* __restrict__ sq2)
{
    __shared__ short As[64 * G2_LDA];    // 9.2 KB
    __shared__ short Bs[192 * G2_LDB];   // 27.6 KB
    __shared__ float sc[FHID], sh[FHID]; // 3 KB
    int tid = threadIdx.x;
    int m0 = blockIdx.x * 64;
    int lane = tid & 63;
    int w = tid >> 6, wr = w >> 1, wc = w & 1;
    int l15 = lane & 15, lk = (lane >> 4) * 8;

    for (int i = tid; i < FHID; i += 256) { sc[i] = scale1[i]; sh[i] = shift1[i]; }

    // per-thread staging coords (fixed across phases)
    const int aRow = tid >> 2,        aK8 = (tid & 3) * 8;       // idx=tid*? -> A: 64x64 = 512 vec8, 2/thread
    short8v pa[2], pb[6];

    // A slots: idx = tid + l*256, row = idx>>3, k8 = (idx&7)*8  (512 vec8)
    // B slots: idx = tid + l*256, row = idx>>3, k8 = (idx&7)*8  (1536 vec8)
    (void)aRow; (void)aK8;

    auto LOAD = [&](int k0) {
        #pragma unroll
        for (int l = 0; l < 2; ++l) {
            int idx = tid + l * 256;
            int am = idx >> 3, k8 = (idx & 7) * 8;
            int gm = m0 + am;
            pa[l] = (gm < NN)
                ? *(const short8v*)(h1 + (size_t)gm * FHID + k0 + k8)
                : (short8v)(short)0;
        }
        #pragma unroll
        for (int l = 0; l < 6; ++l) {
            int idx = tid + l * 256;
            int bn = idx >> 3, k8 = (idx & 7) * 8;
            pb[l] = *(const short8v*)(W2T + (size_t)bn * FHID + k0 + k8);
        }
    };
    auto WRITE = [&](int k0) {
        #pragma unroll
        for (int l = 0; l < 2; ++l) {
            int idx = tid + l * 256;
            int am = idx >> 3, k8 = (idx & 7) * 8;
            short8v v;
            #pragma unroll
            for (int j = 0; j < 8; ++j) {
                int k = k0 + k8 + j;
                float t = sc[k] * b2f((unsigned short)pa[l][j]) + sh[k];
                float e = t > 0.f ? t : __expf(t) - 1.f;
                v[j] = (short)f2b(e);
            }
            *(short8v*)&As[am * G2_LDA + k8] = v;
        }
        #pragma unroll
        for (int l = 0; l < 6; ++l) {
            int idx = tid + l * 256;
            int bn = idx >> 3, k8 = (idx & 7) * 8;
            *(short8v*)&Bs[bn * G2_LDB + k8] = pb[l];
        }
    };

    f32x4 acc[2][6];
    #pragma unroll
    for (int a = 0; a < 2; ++a)
        #pragma unroll
        for (int b = 0; b < 6; ++b) acc[a][b] = (f32x4)(0.f);

    LOAD(0);
    __syncthreads();        // sc/sh ready
    WRITE(0);
    __syncthreads();

    for (int t = 0; t < 6; ++t) {
        if (t < 5) LOAD((t + 1) * 64);          // prefetch next phase (global)
        #pragma unroll
        for (int ks = 0; ks < 2; ++ks) {        // compute current phase
            short8v af[2], bf[6];
            #pragma unroll
            for (int f = 0; f < 2; ++f)
                af[f] = *(short8v*)&As[(wr*32 + f*16 + l15) * G2_LDA + ks*32 + lk];
            #pragma unroll
            for (int g = 0; g < 6; ++g)
                bf[g] = *(short8v*)&Bs[(wc*96 + g*16 + l15) * G2_LDB + ks*32 + lk];
            #pragma unroll
            for (int fm = 0; fm < 2; ++fm)
                #pragma unroll
                for (int fn = 0; fn < 6; ++fn)
                    acc[fm][fn] = __builtin_amdgcn_mfma_f32_16x16x32_bf16(
                        af[fm], bf[fn], acc[fm][fn], 0, 0, 0);
        }
        __syncthreads();
        if (t < 5) {
            WRITE((t + 1) * 64);                // BN+ELU in regs, then LDS
            __syncthreads();
        }
    }

    // epilogue: bias, fp32 store (pre-BN2), column stats
    float bias[6], cs[6], cq[6];
    #pragma unroll
    for (int fn = 0; fn < 6; ++fn) {
        bias[fn] = b2[wc*96 + fn*16 + l15];
        cs[fn] = 0.f; cq[fn] = 0.f;
    }
    #pragma unroll
    for (int fm = 0; fm < 2; ++fm) {
        int mb = m0 + wr*32 + fm*16 + (lane >> 4) * 4;
        #pragma unroll
        for (int r = 0; r < 4; ++r) {
            int gm = mb + r;
            if (gm < NN) {
                #pragma unroll
                for (int fn = 0; fn < 6; ++fn) {
                    float v = acc[fm][fn][r] + bias[fn];
                    cs[fn] += v; cq[fn] += v * v;
                    out[(size_t)gm * FOUT + wc*96 + fn*16 + l15] = v;
                }
            }
        }
    }
    #pragma unroll
    for (int fn = 0; fn < 6; ++fn) {
        cs[fn] += __shfl_xor(cs[fn], 16); cs[fn] += __shfl_xor(cs[fn], 32);
        cq[fn] += __shfl_xor(cq[fn], 16); cq[fn] += __shfl_xor(cq[fn], 32);
    }
    __syncthreads();               // all LDS frag reads done; reuse As
    float* sS = (float*)As;        // [4 waves][96] sum, then [4][96] sq
    if (lane < 16) {
        #pragma unroll
        for (int fn = 0; fn < 6; ++fn) {
            sS[w * 96 + fn * 16 + l15]       = cs[fn];
            sS[384 + w * 96 + fn * 16 + l15] = cq[fn];
        }
    }
    __syncthreads();
    if (tid < 192) {   // col c = tid; partials at waves {wc, wc+2}
        float s = sS[tid] + sS[192 + tid];
        float q = sS[384 + tid] + sS[384 + 192 + tid];
        atomicAdd(sum2 + tid, s);
        atomicAdd(sq2 + tid, q);
    }
}

// ---------------- BN2 + ELU, in-place ------------------------------------
__global__ __launch_bounds__(256) void bn2_elu_kernel(
    float* __restrict__ out, const float* __restrict__ scale2,
    const float* __restrict__ shift2)
{
    int gid = blockIdx.x * 256 + threadIdx.x;
    if (gid >= NN * FOUT / 4) return;
    size_t base = (size_t)gid * 4;
    int c0 = (int)(base % FOUT);
    float4 h = *(float4*)(out + base);
    float hv[4] = {h.x, h.y, h.z, h.w};
    float rv[4];
    #pragma unroll
    for (int j = 0; j < 4; ++j) {
        float t = scale2[c0 + j] * hv[j] + shift2[c0 + j];
        rv[j] = t > 0.f ? t : __expf(t) - 1.f;
    }
    *(float4*)(out + base) = make_float4(rv[0], rv[1], rv[2], rv[3]);
}

__global__ __launch_bounds__(256) void zero_out_kernel(float* out, int n) {
    int gid = blockIdx.x * 256 + threadIdx.x;
    if (gid < n) out[gid] = 0.f;
}

extern "C" void kernel_launch(void* const* d_in, const int* in_sizes, int n_in,
                              void* d_out, int out_size, void* d_ws, size_t ws_size,
                              hipStream_t stream) {
    const float* x    = (const float*)d_in[0];
    const float* val  = (const float*)d_in[1];
    const float* W1   = (const float*)d_in[2];
    const float* b1   = (const float*)d_in[3];
    const float* g1   = (const float*)d_in[4];
    const float* be1  = (const float*)d_in[5];
    const float* W2   = (const float*)d_in[6];
    const float* b2   = (const float*)d_in[7];
    const float* g2   = (const float*)d_in[8];
    const float* be2  = (const float*)d_in[9];
    const float* epsp = (const float*)d_in[10];
    const int* row    = (const int*)d_in[11];
    const int* col    = (const int*)d_in[12];
    float* out = (float*)d_out;

    // ws layout (float idx):
    //      0 sum1[384] | 384 sq1[384] | 768 sum2[192] | 960 sq2[192]
    //   1152 scale1[384] | 1536 shift1[384] | 1920 scale2[192] | 2112 shift2[192]
    //   2304 deg/cursor int[50000] | 52304 offs int[50001] | 102305 bsum[256]
    //  102564 W1T ushort[36864]   (18432 f)
    //  120996 W2T ushort[73728]   (36864 f)
    //  157860 aggb ushort[4.8M]   (2.4M f)
    // 2557860 h1 bf16[19.2M]      (9.6M f); epack int2[800K] aliases h1
    //         (dead before gemm1 writes h1) -> need = 12157860 f = 48.6 MB
    const size_t need = (size_t)12157860 * sizeof(float);
    if (ws_size < need) {
        zero_out_kernel<<<(out_size + 255) / 256, 256, 0, stream>>>(out, out_size);
        return;
    }
    float* ws     = (float*)d_ws;
    float* sum1   = ws;
    float* sq1    = ws + 384;
    float* sum2   = ws + 768;
    float* sq2    = ws + 960;
    float* scale1 = ws + 1152;
    float* shift1 = ws + 1536;
    float* scale2 = ws + 1920;
    float* shift2 = ws + 2112;
    int*   deg    = (int*)(ws + 2304);
    int*   offs   = (int*)(ws + 52304);
    int*   bsum   = (int*)(ws + 102305);
    unsigned short* W1T  = (unsigned short*)(ws + 102564);
    unsigned short* W2T  = (unsigned short*)(ws + 120996);
    unsigned short* aggb = (unsigned short*)(ws + 157860);
    unsigned short* h1   = (unsigned short*)(ws + 2557860);
    int2*  epack  = (int2*)(ws + 2557860);          // alias h1 (dead early)

    hipMemsetAsync(d_ws, 0, 52304 * sizeof(float), stream);   // stats + deg

    prep_w_kernel<<<(FHID*FIN + FOUT*FHID + 255) / 256, 256, 0, stream>>>(
        W1, W2, W1T, W2T);

    hist_kernel<<<(EE + 255) / 256, 256, 0, stream>>>(row, deg);
    scan_partial_kernel<<<NBLK_SCAN, 256, 0, stream>>>(deg, bsum);
    scan_tot_kernel<<<1, 256, 0, stream>>>(bsum, offs);
    scan_final_kernel<<<NBLK_SCAN, 256, 0, stream>>>(deg, bsum, offs);
    scatter_kernel<<<(EE + 255) / 256, 256, 0, stream>>>(row, col, val, deg,
                                                         epack);
    gather_kernel<<<(NN + 7) / 8, 256, 0, stream>>>(x, offs, epack, epsp, aggb);

    dim3 grid1((NN + 127) / 128, 3, 1);
    gemm1_mfma_kernel<<<grid1, 256, 0, stream>>>(aggb, W1T, b1, h1, sum1, sq1);
    bnparam_kernel<<<2, 256, 0, stream>>>(sum1, sq1, g1, be1, scale1, shift1, FHID);

    gemm2_mfma_kernel<<<(NN + 63) / 64, 256, 0, stream>>>(
        h1, W2T, b2, scale1, shift1, out, sum2, sq2);
    bnparam_kernel<<<1, 256, 0, stream>>>(sum2, sq2, g2, be2, scale2, shift2, FOUT);

    bn2_elu_kernel<<<(NN * FOUT / 4 + 255) / 256, 256, 0, stream>>>(
        out, scale2, shift2);
}